// Round 4
// baseline (879.690 us; speedup 1.0000x reference)
//
#include <hip/hip_runtime.h>

#define N_NODES 100000
#define N_EDGES 1600000
#define IN_F 128
#define OUT_F 64

#define NBUCKET 782          // ceil(100000 / 128) buckets of 128 dst rows
#define BROWS 128            // rows per bucket
#define NHBLK 256            // histogram/reorder blocks
#define EPB (N_EDGES / NHBLK)  // 6250 edges per hist block
#define EB 8                 // edges per gather wave-batch

// ---------------- Kernel 1: support = X @ W (fp32 vector ALU) ----------------
// 64x64 tile per 256-thread block; thread = 4 rows x 4 cols; both operands read
// as ds_read_b128. x LDS padded (33 float4 per row) so the 4 row-addresses per
// wave land on 2 bank groups (2-way alias = free) instead of 4-way.
__global__ __launch_bounds__(256) void gemm_kernel(
    const float* __restrict__ x, const float* __restrict__ w,
    float* __restrict__ support) {
    __shared__ float4 w4_lds[IN_F * 16];     // [k][16 float4] = 32 KB
    __shared__ float4 x4_lds[64 * 33];       // 64 rows x 32 f4 (+1 f4 pad) = 33.8 KB

    const int t = threadIdx.x;
    const int rowbase = blockIdx.x * 64;
    {   // stage W: 2048 float4
        const float4* w4 = (const float4*)w;
        #pragma unroll
        for (int i = 0; i < 8; ++i) w4_lds[t + 256 * i] = w4[t + 256 * i];
    }
    {   // stage X tile: 2048 float4 (rows clamped; OOB rows never stored)
        const float4* xg = (const float4*)x;
        #pragma unroll
        for (int i = 0; i < 8; ++i) {
            const int f4i = t + 256 * i;
            const int r = f4i >> 5, kk = f4i & 31;
            const int gr = min(rowbase + r, N_NODES - 1);
            x4_lds[r * 33 + kk] = xg[(size_t)gr * 32 + kk];
        }
    }
    __syncthreads();

    const int cg = t & 15;   // cols cg*4 .. cg*4+3
    const int rg = t >> 4;   // rows rg*4 .. rg*4+3
    float4 acc[4];
    #pragma unroll
    for (int j = 0; j < 4; ++j) acc[j] = make_float4(0.f, 0.f, 0.f, 0.f);

    #pragma unroll 4
    for (int k4 = 0; k4 < 32; ++k4) {
        float4 wv[4], xv[4];
        #pragma unroll
        for (int q = 0; q < 4; ++q) wv[q] = w4_lds[(k4 * 4 + q) * 16 + cg];
        #pragma unroll
        for (int j = 0; j < 4; ++j) xv[j] = x4_lds[(rg * 4 + j) * 33 + k4];
        #pragma unroll
        for (int j = 0; j < 4; ++j) {
            acc[j].x += xv[j].x * wv[0].x + xv[j].y * wv[1].x + xv[j].z * wv[2].x + xv[j].w * wv[3].x;
            acc[j].y += xv[j].x * wv[0].y + xv[j].y * wv[1].y + xv[j].z * wv[2].y + xv[j].w * wv[3].y;
            acc[j].z += xv[j].x * wv[0].z + xv[j].y * wv[1].z + xv[j].z * wv[2].z + xv[j].w * wv[3].z;
            acc[j].w += xv[j].x * wv[0].w + xv[j].y * wv[1].w + xv[j].z * wv[2].w + xv[j].w * wv[3].w;
        }
    }

    #pragma unroll
    for (int j = 0; j < 4; ++j) {
        const int r = rowbase + rg * 4 + j;
        if (r < N_NODES) *(float4*)&support[(size_t)r * OUT_F + cg * 4] = acc[j];
    }
}

// ---------------- Kernel 2: per-block LDS histogram of dst buckets ----------------
__global__ __launch_bounds__(256) void hist_kernel(const int* __restrict__ erow,
                                                   int* __restrict__ C) {
    __shared__ int h[NBUCKET];
    for (int i = threadIdx.x; i < NBUCKET; i += 256) h[i] = 0;
    __syncthreads();
    const int e0 = blockIdx.x * EPB;
    for (int i = threadIdx.x; i < EPB; i += 256)
        atomicAdd(&h[erow[e0 + i] >> 7], 1);
    __syncthreads();
    for (int i = threadIdx.x; i < NBUCKET; i += 256)
        C[i * NHBLK + blockIdx.x] = h[i];   // one global atomic-free store each
}

// ---------------- Kernel 3: exclusive scan of each bucket's 256 block-counts ----------------
__global__ void scan_kernel(int* __restrict__ C, int* __restrict__ base) {
    const int k = blockIdx.x;        // bucket
    const int lane = threadIdx.x;    // 64 threads = 1 wave
    int v[4];
    #pragma unroll
    for (int j = 0; j < 4; ++j) v[j] = C[k * NHBLK + lane * 4 + j];
    const int s = v[0] + v[1] + v[2] + v[3];
    int incl = s;
    #pragma unroll
    for (int d = 1; d < 64; d <<= 1) { int tv = __shfl_up(incl, d); if (lane >= d) incl += tv; }
    int run = incl - s;
    #pragma unroll
    for (int j = 0; j < 4; ++j) { const int old = v[j]; C[k * NHBLK + lane * 4 + j] = run; run += old; }
    if (lane == 63) base[k] = incl;  // bucket total
}

// ---------------- Kernel 4: exclusive scan of bucket totals (one wave) ----------------
__global__ void base_kernel(int* __restrict__ base) {
    const int lane = threadIdx.x;    // 64 threads
    int v[13]; int s = 0;
    #pragma unroll
    for (int j = 0; j < 13; ++j) { const int i = lane * 13 + j; v[j] = (i < NBUCKET) ? base[i] : 0; s += v[j]; }
    int incl = s;
    #pragma unroll
    for (int d = 1; d < 64; d <<= 1) { int tv = __shfl_up(incl, d); if (lane >= d) incl += tv; }
    int run = incl - s;
    #pragma unroll
    for (int j = 0; j < 13; ++j) { const int i = lane * 13 + j; if (i < NBUCKET) base[i] = run; run += v[j]; }
    if (lane == 63) base[NBUCKET] = incl;   // grand total = N_EDGES
}

// ---------------- Kernel 5: reorder edges into bucket-contiguous arrays ----------------
// rec packs src (bits 0..19) and dst-within-bucket (bits 20..26).
__global__ __launch_bounds__(256) void reorder_kernel(
    const int* __restrict__ erow, const int* __restrict__ ecol,
    const float* __restrict__ evals, const int* __restrict__ C,
    const int* __restrict__ base, int* __restrict__ srec, float* __restrict__ sval) {
    __shared__ int loff[NBUCKET];
    for (int i = threadIdx.x; i < NBUCKET; i += 256)
        loff[i] = base[i] + C[i * NHBLK + blockIdx.x];
    __syncthreads();
    const int e0 = blockIdx.x * EPB;
    for (int i = threadIdx.x; i < EPB; i += 256) {
        const int e = e0 + i;
        const int dst = erow[e];
        const int p = atomicAdd(&loff[dst >> 7], 1);   // LDS atomic
        srec[p] = ecol[e] | ((dst & 127) << 20);
        sval[p] = evals[e];
    }
}

// ---------------- Kernel 6: gather + LDS accumulate + bias (no global atomics) ----------------
__global__ __launch_bounds__(256) void gather_kernel(
    const float* __restrict__ support, const int* __restrict__ srec,
    const float* __restrict__ sval, const int* __restrict__ base,
    const float* __restrict__ bias, float* __restrict__ out) {
    __shared__ float acc[BROWS * OUT_F];   // 32 KB
    const int t = threadIdx.x;
    #pragma unroll
    for (int i = 0; i < BROWS * OUT_F / 256; ++i) acc[t + i * 256] = 0.f;
    __syncthreads();

    const int k = blockIdx.x;
    const int wid = t >> 6, lane = t & 63;
    const int start = base[k], end = base[k + 1];

    int e0 = start + wid * EB;
    for (; e0 + EB <= end; e0 += 4 * EB) {             // full batches
        const int eu = __builtin_amdgcn_readfirstlane(e0);
        int rec[EB]; float val[EB];
        #pragma unroll
        for (int u = 0; u < EB; ++u) { rec[u] = srec[eu + u]; val[u] = sval[eu + u]; }
        float g[EB];
        #pragma unroll
        for (int u = 0; u < EB; ++u)
            g[u] = support[(size_t)(rec[u] & 0xFFFFF) * OUT_F + lane] * val[u];
        #pragma unroll
        for (int u = 0; u < EB; ++u)
            atomicAdd(&acc[(rec[u] >> 20) * OUT_F + lane], g[u]);   // ds_add_f32
    }
    if (e0 < end) {                                     // tail
        const int eu = __builtin_amdgcn_readfirstlane(e0);
        const int n = end - eu;
        for (int u = 0; u < n; ++u) {
            const int rec = srec[eu + u];
            const float g = support[(size_t)(rec & 0xFFFFF) * OUT_F + lane] * sval[eu + u];
            atomicAdd(&acc[(rec >> 20) * OUT_F + lane], g);
        }
    }
    __syncthreads();

    const int row0 = k * BROWS;
    const float b = bias[t & 63];
    for (int i = t; i < BROWS * OUT_F; i += 256) {
        const int r = row0 + (i >> 6);
        if (r < N_NODES) out[(size_t)r * OUT_F + (i & 63)] = acc[i] + b;
    }
}

// ---------------- Fallback (ws too small): bias-init + atomic scatter ----------------
__global__ __launch_bounds__(256) void init_out_kernel(const float* __restrict__ bias,
                                                       float* __restrict__ out) {
    const size_t i = (size_t)blockIdx.x * 256 + threadIdx.x;
    if (i < (size_t)N_NODES * OUT_F) out[i] = bias[i & 63];
}
__global__ __launch_bounds__(256) void scatter_atomic_kernel(
    const float* __restrict__ support, const int* __restrict__ erow,
    const int* __restrict__ ecol, const float* __restrict__ evals,
    float* __restrict__ out) {
    const int wid = (blockIdx.x * 256 + threadIdx.x) >> 6;
    const int nw = gridDim.x * 4;
    const int lane = threadIdx.x & 63;
    const int n_iters = N_EDGES / EB;
    for (int it0 = wid; it0 < n_iters; it0 += nw) {
        const int e0 = __builtin_amdgcn_readfirstlane(it0) * EB;
        int src[EB], dst[EB]; float val[EB];
        #pragma unroll
        for (int u = 0; u < EB; ++u) { src[u] = ecol[e0 + u]; dst[u] = erow[e0 + u]; val[u] = evals[e0 + u]; }
        float g[EB];
        #pragma unroll
        for (int u = 0; u < EB; ++u) g[u] = support[(size_t)src[u] * OUT_F + lane];
        #pragma unroll
        for (int u = 0; u < EB; ++u) atomicAdd(&out[(size_t)dst[u] * OUT_F + lane], g[u] * val[u]);
    }
}

extern "C" void kernel_launch(void* const* d_in, const int* in_sizes, int n_in,
                              void* d_out, int out_size, void* d_ws, size_t ws_size,
                              hipStream_t stream) {
    const float* x     = (const float*)d_in[0];
    const float* w     = (const float*)d_in[1];
    const float* bias  = (const float*)d_in[2];
    const int* erow    = (const int*)d_in[3];
    const int* ecol    = (const int*)d_in[4];
    const float* evals = (const float*)d_in[5];
    float* out = (float*)d_out;

    // workspace layout
    char* p = (char*)d_ws;
    float* support = (float*)p;                       size_t o = (size_t)N_NODES * OUT_F * 4;  // 25.6 MB
    int* C    = (int*)(p + o);                        o += (size_t)NBUCKET * NHBLK * 4;        // 800 KB
    int* base = (int*)(p + o);                        o += ((NBUCKET + 1) * 4 + 255) / 256 * 256;
    int* srec = (int*)(p + o);                        o += (size_t)N_EDGES * 4;                // 6.4 MB
    float* sval = (float*)(p + o);                    o += (size_t)N_EDGES * 4;                // 6.4 MB

    gemm_kernel<<<(N_NODES + 63) / 64, 256, 0, stream>>>(x, w, support);

    if (ws_size >= o) {
        hist_kernel<<<NHBLK, 256, 0, stream>>>(erow, C);
        scan_kernel<<<NBUCKET, 64, 0, stream>>>(C, base);
        base_kernel<<<1, 64, 0, stream>>>(base);
        reorder_kernel<<<NHBLK, 256, 0, stream>>>(erow, ecol, evals, C, base, srec, sval);
        gather_kernel<<<NBUCKET, 256, 0, stream>>>(support, srec, sval, base, bias, out);
    } else {
        init_out_kernel<<<((N_NODES * OUT_F) + 255) / 256, 256, 0, stream>>>(bias, out);
        scatter_atomic_kernel<<<2048, 256, 0, stream>>>(support, erow, ecol, evals, out);
    }
}

// Round 5
// 800.496 us; speedup vs baseline: 1.0989x; 1.0989x over previous
//
#include <hip/hip_runtime.h>

#define N_NODES 100000
#define N_EDGES 1600000
#define IN_F 128
#define OUT_F 64

#define BROWS 32             // rows per bucket (100000 = 32 * 3125 exactly)
#define NBUCKET 3125
#define NHBLK 128            // histogram/reorder blocks
#define EPB (N_EDGES / NHBLK)  // 12500 edges per hist block
#define EB 16                // edges per gather wave-batch (MLP)

// ---------------- Kernel 1: support = X @ W (fp32 vector ALU) ----------------
__global__ __launch_bounds__(256) void gemm_kernel(
    const float* __restrict__ x, const float* __restrict__ w,
    float* __restrict__ support) {
    __shared__ float4 w4_lds[IN_F * 16];     // 32 KB
    __shared__ float4 x4_lds[64 * 33];       // 33.8 KB (pad kills 4-way conflict)

    const int t = threadIdx.x;
    const int rowbase = blockIdx.x * 64;
    {
        const float4* w4 = (const float4*)w;
        #pragma unroll
        for (int i = 0; i < 8; ++i) w4_lds[t + 256 * i] = w4[t + 256 * i];
    }
    {
        const float4* xg = (const float4*)x;
        #pragma unroll
        for (int i = 0; i < 8; ++i) {
            const int f4i = t + 256 * i;
            const int r = f4i >> 5, kk = f4i & 31;
            const int gr = min(rowbase + r, N_NODES - 1);
            x4_lds[r * 33 + kk] = xg[(size_t)gr * 32 + kk];
        }
    }
    __syncthreads();

    const int cg = t & 15;
    const int rg = t >> 4;
    float4 acc[4];
    #pragma unroll
    for (int j = 0; j < 4; ++j) acc[j] = make_float4(0.f, 0.f, 0.f, 0.f);

    #pragma unroll 4
    for (int k4 = 0; k4 < 32; ++k4) {
        float4 wv[4], xv[4];
        #pragma unroll
        for (int q = 0; q < 4; ++q) wv[q] = w4_lds[(k4 * 4 + q) * 16 + cg];
        #pragma unroll
        for (int j = 0; j < 4; ++j) xv[j] = x4_lds[(rg * 4 + j) * 33 + k4];
        #pragma unroll
        for (int j = 0; j < 4; ++j) {
            acc[j].x += xv[j].x * wv[0].x + xv[j].y * wv[1].x + xv[j].z * wv[2].x + xv[j].w * wv[3].x;
            acc[j].y += xv[j].x * wv[0].y + xv[j].y * wv[1].y + xv[j].z * wv[2].y + xv[j].w * wv[3].y;
            acc[j].z += xv[j].x * wv[0].z + xv[j].y * wv[1].z + xv[j].z * wv[2].z + xv[j].w * wv[3].z;
            acc[j].w += xv[j].x * wv[0].w + xv[j].y * wv[1].w + xv[j].z * wv[2].w + xv[j].w * wv[3].w;
        }
    }

    #pragma unroll
    for (int j = 0; j < 4; ++j) {
        const int r = rowbase + rg * 4 + j;
        if (r < N_NODES) *(float4*)&support[(size_t)r * OUT_F + cg * 4] = acc[j];
    }
}

// ---------------- Kernel 2: per-block LDS histogram of dst buckets ----------------
__global__ __launch_bounds__(256) void hist_kernel(const int* __restrict__ erow,
                                                   int* __restrict__ C) {
    __shared__ int h[NBUCKET];   // 12.5 KB
    for (int i = threadIdx.x; i < NBUCKET; i += 256) h[i] = 0;
    __syncthreads();
    const int e0 = blockIdx.x * EPB;
    for (int i = threadIdx.x; i < EPB; i += 256)
        atomicAdd(&h[erow[e0 + i] >> 5], 1);
    __syncthreads();
    for (int i = threadIdx.x; i < NBUCKET; i += 256)
        C[i * NHBLK + blockIdx.x] = h[i];
}

// ---------------- Kernel 3: exclusive scan of each bucket's block-counts ----------------
__global__ void scan_kernel(int* __restrict__ C, int* __restrict__ base) {
    const int k = blockIdx.x;        // bucket
    const int lane = threadIdx.x;    // 64 threads
    int v[NHBLK / 64];
    #pragma unroll
    for (int j = 0; j < NHBLK / 64; ++j) v[j] = C[k * NHBLK + lane * (NHBLK / 64) + j];
    int s = 0;
    #pragma unroll
    for (int j = 0; j < NHBLK / 64; ++j) s += v[j];
    int incl = s;
    #pragma unroll
    for (int d = 1; d < 64; d <<= 1) { int tv = __shfl_up(incl, d); if (lane >= d) incl += tv; }
    int run = incl - s;
    #pragma unroll
    for (int j = 0; j < NHBLK / 64; ++j) { const int old = v[j]; C[k * NHBLK + lane * (NHBLK / 64) + j] = run; run += old; }
    if (lane == 63) base[k] = incl;
}

// ---------------- Kernel 4: exclusive scan of bucket totals (one wave) ----------------
#define BPL ((NBUCKET + 63) / 64)   // 49 per lane
__global__ void base_kernel(int* __restrict__ base) {
    const int lane = threadIdx.x;
    int v[BPL]; int s = 0;
    #pragma unroll
    for (int j = 0; j < BPL; ++j) { const int i = lane * BPL + j; v[j] = (i < NBUCKET) ? base[i] : 0; s += v[j]; }
    int incl = s;
    #pragma unroll
    for (int d = 1; d < 64; d <<= 1) { int tv = __shfl_up(incl, d); if (lane >= d) incl += tv; }
    int run = incl - s;
    #pragma unroll
    for (int j = 0; j < BPL; ++j) { const int i = lane * BPL + j; if (i < NBUCKET) base[i] = run; run += v[j]; }
    if (lane == 63) base[NBUCKET] = incl;
}

// ---------------- Kernel 5: reorder edges into bucket-contiguous arrays ----------------
// rec packs src (bits 0..19) and dst-within-bucket (bits 20..24).
__global__ __launch_bounds__(256) void reorder_kernel(
    const int* __restrict__ erow, const int* __restrict__ ecol,
    const float* __restrict__ evals, const int* __restrict__ C,
    const int* __restrict__ base, int* __restrict__ srec, float* __restrict__ sval) {
    __shared__ int loff[NBUCKET];   // 12.5 KB
    for (int i = threadIdx.x; i < NBUCKET; i += 256)
        loff[i] = base[i] + C[i * NHBLK + blockIdx.x];
    __syncthreads();
    const int e0 = blockIdx.x * EPB;
    for (int i = threadIdx.x; i < EPB; i += 256) {
        const int e = e0 + i;
        const int dst = erow[e];
        const int p = atomicAdd(&loff[dst >> 5], 1);   // LDS atomic
        srec[p] = ecol[e] | ((dst & 31) << 20);
        sval[p] = evals[e];
    }
}

// ---------------- Kernel 6: gather + LDS accumulate + bias (no global atomics) ----------------
__global__ __launch_bounds__(256) void gather_kernel(
    const float* __restrict__ support, const int* __restrict__ srec,
    const float* __restrict__ sval, const int* __restrict__ base,
    const float* __restrict__ bias, float* __restrict__ out) {
    __shared__ float acc[BROWS * OUT_F];   // 8 KB
    const int t = threadIdx.x;
    #pragma unroll
    for (int i = 0; i < BROWS * OUT_F / 256; ++i) acc[t + i * 256] = 0.f;
    __syncthreads();

    const int k = blockIdx.x;
    const int wid = t >> 6, lane = t & 63;
    const int start = base[k], end = base[k + 1];

    int e0 = start + wid * EB;
    for (; e0 + EB <= end; e0 += 4 * EB) {
        const int eu = __builtin_amdgcn_readfirstlane(e0);
        int rec[EB]; float val[EB];
        #pragma unroll
        for (int u = 0; u < EB; ++u) { rec[u] = srec[eu + u]; val[u] = sval[eu + u]; }
        float g[EB];
        #pragma unroll
        for (int u = 0; u < EB; ++u)
            g[u] = support[(size_t)(rec[u] & 0xFFFFF) * OUT_F + lane] * val[u];
        #pragma unroll
        for (int u = 0; u < EB; ++u)
            atomicAdd(&acc[(rec[u] >> 20) * OUT_F + lane], g[u]);   // ds_add_f32
    }
    if (e0 < end) {                                     // exactly one wave hits this
        const int eu = __builtin_amdgcn_readfirstlane(e0);
        const int n = end - eu;
        for (int u = 0; u < n; ++u) {
            const int rec = srec[eu + u];
            const float g = support[(size_t)(rec & 0xFFFFF) * OUT_F + lane] * sval[eu + u];
            atomicAdd(&acc[(rec >> 20) * OUT_F + lane], g);
        }
    }
    __syncthreads();

    const int row0 = k * BROWS;
    const float b = bias[t & 63];
    #pragma unroll
    for (int i = t; i < BROWS * OUT_F; i += 256)
        out[(size_t)(row0 + (i >> 6)) * OUT_F + (i & 63)] = acc[i] + b;
}

// ---------------- Fallback (ws too small): bias-init + atomic scatter ----------------
__global__ __launch_bounds__(256) void init_out_kernel(const float* __restrict__ bias,
                                                       float* __restrict__ out) {
    const size_t i = (size_t)blockIdx.x * 256 + threadIdx.x;
    if (i < (size_t)N_NODES * OUT_F) out[i] = bias[i & 63];
}
__global__ __launch_bounds__(256) void scatter_atomic_kernel(
    const float* __restrict__ support, const int* __restrict__ erow,
    const int* __restrict__ ecol, const float* __restrict__ evals,
    float* __restrict__ out) {
    const int wid = (blockIdx.x * 256 + threadIdx.x) >> 6;
    const int nw = gridDim.x * 4;
    const int lane = threadIdx.x & 63;
    const int n_iters = N_EDGES / 8;
    for (int it0 = wid; it0 < n_iters; it0 += nw) {
        const int e0 = __builtin_amdgcn_readfirstlane(it0) * 8;
        int src[8], dst[8]; float val[8];
        #pragma unroll
        for (int u = 0; u < 8; ++u) { src[u] = ecol[e0 + u]; dst[u] = erow[e0 + u]; val[u] = evals[e0 + u]; }
        float g[8];
        #pragma unroll
        for (int u = 0; u < 8; ++u) g[u] = support[(size_t)src[u] * OUT_F + lane];
        #pragma unroll
        for (int u = 0; u < 8; ++u) atomicAdd(&out[(size_t)dst[u] * OUT_F + lane], g[u] * val[u]);
    }
}

extern "C" void kernel_launch(void* const* d_in, const int* in_sizes, int n_in,
                              void* d_out, int out_size, void* d_ws, size_t ws_size,
                              hipStream_t stream) {
    const float* x     = (const float*)d_in[0];
    const float* w     = (const float*)d_in[1];
    const float* bias  = (const float*)d_in[2];
    const int* erow    = (const int*)d_in[3];
    const int* ecol    = (const int*)d_in[4];
    const float* evals = (const float*)d_in[5];
    float* out = (float*)d_out;

    char* p = (char*)d_ws;
    float* support = (float*)p;                       size_t o = (size_t)N_NODES * OUT_F * 4;  // 25.6 MB
    int* C    = (int*)(p + o);                        o += (size_t)NBUCKET * NHBLK * 4;        // 1.6 MB
    int* base = (int*)(p + o);                        o += ((NBUCKET + 1) * 4 + 255) / 256 * 256;
    int* srec = (int*)(p + o);                        o += (size_t)N_EDGES * 4;                // 6.4 MB
    float* sval = (float*)(p + o);                    o += (size_t)N_EDGES * 4;                // 6.4 MB

    gemm_kernel<<<(N_NODES + 63) / 64, 256, 0, stream>>>(x, w, support);

    if (ws_size >= o) {
        hist_kernel<<<NHBLK, 256, 0, stream>>>(erow, C);
        scan_kernel<<<NBUCKET, 64, 0, stream>>>(C, base);
        base_kernel<<<1, 64, 0, stream>>>(base);
        reorder_kernel<<<NHBLK, 256, 0, stream>>>(erow, ecol, evals, C, base, srec, sval);
        gather_kernel<<<NBUCKET, 256, 0, stream>>>(support, srec, sval, base, bias, out);
    } else {
        init_out_kernel<<<((N_NODES * OUT_F) + 255) / 256, 256, 0, stream>>>(bias, out);
        scatter_atomic_kernel<<<2048, 256, 0, stream>>>(support, erow, ecol, evals, out);
    }
}